// Round 9
// baseline (123.012 us; speedup 1.0000x reference)
//
#include <hip/hip_runtime.h>

// Problem constants: B=1024, F=33, D=128, A=128, P=F*(F-1)/2=528
#define FN 33
#define DN 128
#define AN 128
#define PN 528
#define MTN 33     // P / 16 M-tiles, exact
#define XS 136     // fp16 row stride for xh in LDS (272 B, 16B-aligned, non-pow2)
#define AS 36      // u32 row stride for attn_h2 (144 B, 16B-aligned)
#define SWS 544    // f32 stride of one row's scores in workspace (16B-aligned)

typedef __attribute__((ext_vector_type(8))) _Float16 half8;
typedef __attribute__((ext_vector_type(2))) _Float16 h2;
typedef __attribute__((ext_vector_type(4))) float f32x4;
typedef __attribute__((ext_vector_type(2))) float f32x2;
typedef __attribute__((ext_vector_type(4))) unsigned int u32x4;

__device__ __forceinline__ unsigned int pkrtz(float a, float b) {
  return __builtin_bit_cast(unsigned int, __builtin_amdgcn_cvt_pkrtz(a, b));
}
__device__ __forceinline__ h2 ash2(unsigned int u) { return __builtin_bit_cast(h2, u); }

// closed-form pair index -> (i, j), i<j, upper-triangle row-major (F=33)
__device__ __forceinline__ int pair_row(int p, int* jout) {
  float s = __builtin_sqrtf((float)(4225 - 8 * p));     // 65^2 - 8p
  int i = (int)((65.0f - s) * 0.5f);
  if ((i * (65 - i)) >> 1 > p) i--;
  if (((i + 1) * (64 - i)) >> 1 <= p) i++;
  *jout = i + 1 + (p - ((i * (65 - i)) >> 1));
  return i;
}

// sum over the 16-lane DPP row via row_ror rotations (VALU pipe, no LDS)
__device__ __forceinline__ float row_sum16(float v) {
  v += __builtin_bit_cast(float, __builtin_amdgcn_update_dpp(0, __builtin_bit_cast(int, v), 0x128, 0xF, 0xF, false));
  v += __builtin_bit_cast(float, __builtin_amdgcn_update_dpp(0, __builtin_bit_cast(int, v), 0x124, 0xF, 0xF, false));
  v += __builtin_bit_cast(float, __builtin_amdgcn_update_dpp(0, __builtin_bit_cast(int, v), 0x122, 0xF, 0xF, false));
  v += __builtin_bit_cast(float, __builtin_amdgcn_update_dpp(0, __builtin_bit_cast(int, v), 0x121, 0xF, 0xF, false));
  return v;
}

// ============ Kernel 1: scores[b][p] = g_b . relu(inner W^T + bias) ============
// One block = one row. 4 waves m-split (mod 4). One barrier (post-staging); no
// softmax / epilogue -> waves exit independently, no phase-lock.
__global__ __launch_bounds__(256, 2)
void afm_scores(const float* __restrict__ gnn, const float* __restrict__ xg,
                const float* __restrict__ Wg,  const float* __restrict__ bg,
                float* __restrict__ sws)
{
  __shared__ __align__(16) _Float16 xh[FN * XS];   // x[b] fp16 [i][d] (8976 B)
  __shared__ unsigned short rowcol[PN];            // i | (j<<8)

  const int tid  = threadIdx.x;     // 0..255
  const int b    = blockIdx.x;
  const int wave = tid >> 6;
  const int lane = tid & 63;
  const int q    = lane >> 4;
  const int u    = lane & 15;

  for (int p = tid; p < PN; p += 256) {
    int j; int i = pair_row(p, &j);
    rowcol[p] = (unsigned short)(i | (j << 8));
  }
  const f32x4* xg4 = (const f32x4*)(xg + (size_t)b * FN * DN);
  for (int idx = tid; idx < (FN * DN) / 4; idx += 256) {   // 1056 float4
    f32x4 v = xg4[idx];
    int i  = idx >> 5;
    int d0 = (idx & 31) << 2;
    *(uint2*)&xh[i * XS + d0] = make_uint2(pkrtz(v.x, v.y), pkrtz(v.z, v.w));
  }

  // B-fragments (full W) pinned; Bf[n][kk]: lane holds W[n*16+u][kk*32+q*8..+7]
  half8 Bf[8][4];
  #pragma unroll
  for (int n = 0; n < 8; n++) {
    const float* wrow = Wg + (size_t)(n * 16 + u) * DN + q * 8;
    #pragma unroll
    for (int kk = 0; kk < 4; kk++) {
      f32x4 w0 = *(const f32x4*)(wrow + kk * 32);
      f32x4 w1 = *(const f32x4*)(wrow + kk * 32 + 4);
      union { half8 h; unsigned int w[4]; } t;
      t.w[0] = pkrtz(w0.x, w0.y);
      t.w[1] = pkrtz(w0.z, w0.w);
      t.w[2] = pkrtz(w1.x, w1.y);
      t.w[3] = pkrtz(w1.z, w1.w);
      Bf[n][kk] = t.h;
      asm volatile("" : "+v"(Bf[n][kk]));   // pin: forbid remat
    }
  }
  float garr[8];
  f32x4 bias_acc[8];                        // bias splat = first MFMA's C operand
  #pragma unroll
  for (int n = 0; n < 8; n++) {
    garr[n] = gnn[(size_t)b * AN + n * 16 + u];
    float bv = bg[n * 16 + u];
    bias_acc[n] = (f32x4){bv, bv, bv, bv};
  }
  __syncthreads();                          // the only barrier

  for (int mt = wave; mt < MTN; mt += 4) {
    const unsigned int rc = rowcol[mt * 16 + u];
    const int r = rc & 255, c = rc >> 8;
    half8 xr[4], xc[4];
    #pragma unroll
    for (int kk = 0; kk < 4; kk++) {
      xr[kk] = *(const half8*)&xh[r * XS + kk * 32 + q * 8];
      xc[kk] = *(const half8*)&xh[c * XS + kk * 32 + q * 8];
    }
    f32x4 acc[8];
    #pragma unroll
    for (int kk = 0; kk < 4; kk++) {
      half8 Af = xr[kk] * xc[kk];           // v_pk_mul_f16 x4
      #pragma unroll
      for (int n = 0; n < 8; n++)
        acc[n] = __builtin_amdgcn_mfma_f32_16x16x32_f16(
            Af, Bf[n][kk], kk == 0 ? bias_acc[n] : acc[n], 0, 0, 0);
    }
    float sc[4] = {0.f, 0.f, 0.f, 0.f};
    #pragma unroll
    for (int n = 0; n < 8; n++)
      #pragma unroll
      for (int rr = 0; rr < 4; rr++) {
        float fmv = fmaxf(acc[n][rr], 0.f); // relu (bias via MFMA C)
        sc[rr] = fmaf(fmv, garr[n], sc[rr]);
      }
    #pragma unroll
    for (int rr = 0; rr < 4; rr++) sc[rr] = row_sum16(sc[rr]);
    if (u == 0)
      *(f32x4*)&sws[(size_t)b * SWS + mt * 16 + q * 4] = (f32x4){sc[0], sc[1], sc[2], sc[3]};
  }
}

// ============ Kernel 2: softmax over 528 + weighted sum + concat ============
// One block (128 thr / 2 waves) = one row. Wave-redundant softmax (no reduce
// barriers); each wave owns attn rows i == wave (mod 2) -> no inter-wave LDS
// dependency. One barrier (partial combine).
__global__ __launch_bounds__(128, 4)
void afm_out(const float* __restrict__ gnn, const float* __restrict__ xg,
             const float* __restrict__ sws, float* __restrict__ out)
{
  __shared__ __align__(16) unsigned int attn_h2[FN * AS]; // exp, dup f16x2
  __shared__ __align__(16) float part[256];

  const int tid  = threadIdx.x;     // 0..127
  const int b    = blockIdx.x;
  const int wave = tid >> 6;
  const int lane = tid & 63;

  // zero this wave's attn rows (i == wave mod 2), incl. pads
  #pragma unroll
  for (int r = 0; r < 16; r++)
    if (lane < AS) attn_h2[(wave + 2 * r) * AS + lane] = 0u;

  // wave-redundant softmax stats over all 528 scores
  const float* srow = sws + (size_t)b * SWS;
  float s[9], e[9];
  #pragma unroll
  for (int t = 0; t < 8; t++) s[t] = srow[t * 64 + lane];
  s[8] = (lane < 16) ? srow[512 + lane] : -3.4e38f;
  float m = s[0];
  #pragma unroll
  for (int t = 1; t < 9; t++) m = fmaxf(m, s[t]);
  #pragma unroll
  for (int off = 32; off >= 1; off >>= 1) m = fmaxf(m, __shfl_xor(m, off, 64));
  float lsum = 0.f;
  #pragma unroll
  for (int t = 0; t < 9; t++) {
    e[t] = (t == 8 && lane >= 16) ? 0.f : __expf(s[t] - m);
    lsum += e[t];
  }
  #pragma unroll
  for (int off = 32; off >= 1; off >>= 1) lsum += __shfl_xor(lsum, off, 64);
  const float Z = lsum;             // identical in both waves

  // scatter exps belonging to this wave's rows
  #pragma unroll
  for (int t = 0; t < 9; t++) {
    if (t == 8 && lane >= 16) continue;
    int p = t * 64 + lane;
    int j; int i = pair_row(p, &j);
    if ((i & 1) == wave)
      attn_h2[i * AS + (j - i - 1)] = pkrtz(e[t], e[t]);
  }

  // x columns d = 2*lane, 2*lane+1 straight from global (L3-hot), as f16x2
  unsigned int xp[36];
  #pragma unroll
  for (int j = 0; j < FN; j++) {
    f32x2 v = *(const f32x2*)&xg[((size_t)b * FN + j) * DN + 2 * lane];
    xp[j] = pkrtz(v.x, v.y);
  }
  xp[33] = 0u; xp[34] = 0u; xp[35] = 0u;

  float a0 = 0.f, a1 = 0.f;
  #pragma unroll
  for (int i = 0; i < 32; i++) {
    if ((i & 1) != wave) continue;   // wave-uniform; reads only own rows
    const int L  = 32 - i;
    const int n4 = (L + 3) >> 2;
    h2 ti2 = (h2)0.0f;
    #pragma unroll
    for (int t = 0; t < 8; t++) {
      if (t >= n4) break;
      u32x4 a4 = *(const u32x4*)&attn_h2[i * AS + 4 * t];  // broadcast, pads 0
      ti2 += ash2(a4.x) * ash2(xp[i + 1 + 4 * t + 0]);     // v_pk_fma_f16
      ti2 += ash2(a4.y) * ash2(xp[i + 1 + 4 * t + 1]);
      ti2 += ash2(a4.z) * ash2(xp[i + 1 + 4 * t + 2]);
      ti2 += ash2(a4.w) * ash2(xp[i + 1 + 4 * t + 3]);
    }
    h2 xi = ash2(xp[i]);
    a0 = fmaf((float)xi[0], (float)ti2[0], a0);
    a1 = fmaf((float)xi[1], (float)ti2[1], a1);
  }
  *(f32x2*)&part[wave * 128 + 2 * lane] = (f32x2){a0, a1};
  __syncthreads();

  float tot = part[tid] + part[128 + tid];
  out[(size_t)b * (AN + DN) + tid] = gnn[(size_t)b * AN + tid];
  out[(size_t)b * (AN + DN) + AN + tid] = tot * (100.0f / Z);
}

extern "C" void kernel_launch(void* const* d_in, const int* in_sizes, int n_in,
                              void* d_out, int out_size, void* d_ws, size_t ws_size,
                              hipStream_t stream) {
  (void)n_in; (void)out_size; (void)ws_size;
  const float* gnn  = (const float*)d_in[0];
  const float* x    = (const float*)d_in[1];
  const float* W    = (const float*)d_in[2];
  const float* bias = (const float*)d_in[3];
  float* out = (float*)d_out;
  float* sws = (float*)d_ws;        // needs Bn*SWS*4 = 2.23 MB of workspace
  const int Bn = in_sizes[0] / AN;  // 1024
  afm_scores<<<dim3(Bn), dim3(256), 0, stream>>>(gnn, x, W, bias, sws);
  afm_out   <<<dim3(Bn), dim3(128), 0, stream>>>(gnn, x, sws, out);
}